// Round 1
// baseline (258.409 us; speedup 1.0000x reference)
//
#include <hip/hip_runtime.h>

// SubManifold gather: out[b,w,i,j] = x[b, idx[w,i], idx[w,j]]
// idx[w=wr*10+wc, i=ai*12+bi] = 192*wr + 4*wc + 48*ai + bi
// D=48, N=2304, K=12 (kk=144), S=4, 10x10=100 windows, BS=8.
//
// Band-structured LDS staging:
//   block = (b, wr, ai, jh):  rows needed = 192*wr+48*ai + [0,48)   (contiguous!)
//                             cols needed = 192*wr+288*jh + [0,288) (contiguous!)
//   Phase 1: coalesced load of the 48x288 fp32 panel into LDS (54 KB).
//   Phase 2: emit out[b, wr*10+wc, 12*ai+bi, j in half jh] from LDS,
//            coalesced 288B output segments.
// Global reads: 1920 blocks * 54 KB = 104 MB (all streaming), writes 66 MB.

namespace {
constexpr int N    = 2304;   // tokens (48*48)
constexpr int NW   = 100;
constexpr int KK   = 144;
constexpr int ROWS = 48;     // staged rows per block
constexpr int COLS = 288;    // staged cols per block
constexpr int LDSC = 292;    // padded LDS row stride (dwords); 292%32=4 rotates banks per row
constexpr int LOAD_F4 = ROWS * (COLS / 4);      // 3456 float4 loads per block
constexpr int OUT_F4  = 10 * 12 * 18;           // 2160 float4 stores per block
}

// XOR-swizzle on the dword column within a row: spreads the aj-stride-96
// (== 0 mod 32 banks) read collision across banks. Involution (bits 5:7
// folded into bits 2:4), preserves 16B alignment (bits 0:1 untouched).
__device__ __forceinline__ int sw(int col) {
    return col ^ (((col >> 5) & 7) << 2);
}

__global__ __launch_bounds__(256, 2) void submanifold_band(
    const float* __restrict__ x, float4* __restrict__ out) {
    __shared__ float xs[ROWS][LDSC];

    // block = (b, wr, ai, jh)
    int blk = blockIdx.x;
    int jh  = blk & 1;
    int t   = blk >> 1;
    int ai  = t % 12;
    int bw  = t / 12;
    int wr  = bw % 10;
    int b   = bw / 10;

    int r0 = 192 * wr + 48 * ai;    // first staged source row (token idx)
    int c0 = 192 * wr + 288 * jh;   // first staged source col

    const float* xb = x + (size_t)b * N * N;

    // ---- Phase 1: contiguous 48x288 panel -> LDS (fully coalesced) ----
    for (int f = threadIdx.x; f < LOAD_F4; f += 256) {
        int row = f / (COLS / 4);            // 0..47
        int c4  = f - row * (COLS / 4);      // 0..71
        float4 v = *reinterpret_cast<const float4*>(
            xb + (size_t)(r0 + row) * N + c0 + 4 * c4);
        *reinterpret_cast<float4*>(&xs[row][sw(4 * c4)]) = v;
    }
    __syncthreads();

    // ---- Phase 2: emit outputs for all (wc, bi, j-half) from LDS ----
    // out float4 index = ((b*100 + wr*10 + wc)*144 + 12*ai + bi)*36 + 18*jh + q
    size_t outbase = ((size_t)(b * NW + wr * 10) * KK + 12 * ai) * (KK / 4) + 18 * jh;
    for (int v = threadIdx.x; v < OUT_F4; v += 256) {
        int q  = v % 18;            // float4 within the 72-float j-half
        int p  = v / 18;
        int bi = p % 12;
        int wc = p / 12;            // 0..9
        int ap  = q / 3;            // aj - 6*jh, 0..5
        int bj4 = (q - ap * 3) * 4; // 0,4,8

        int lrow = 4 * wc + bi;               // source row - r0   (0..47)
        int lcol = 4 * wc + 48 * ap + bj4;    // source col - c0   (0..284)
        float4 val = *reinterpret_cast<const float4*>(&xs[lrow][sw(lcol)]);

        out[outbase + (size_t)wc * (KK * KK / 4) + (size_t)bi * (KK / 4) + q] = val;
    }
}

extern "C" void kernel_launch(void* const* d_in, const int* in_sizes, int n_in,
                              void* d_out, int out_size, void* d_ws, size_t ws_size,
                              hipStream_t stream) {
    const float* x = (const float*)d_in[0];
    float4* out = (float4*)d_out;
    const int blocks = 8 * 10 * 12 * 2;   // (b, wr, ai, jh) = 1920, exact
    submanifold_band<<<blocks, 256, 0, stream>>>(x, out);
}

// Round 3
// 230.466 us; speedup vs baseline: 1.1212x; 1.1212x over previous
//
#include <hip/hip_runtime.h>

// SubManifold gather: out[b,w,i,j] = x[b, idx[w,i], idx[w,j]]
// idx[w=wr*10+wc, i=a*12+b] = 192*wr + 4*wc + 48*a + b
// Static config: D=48, N=2304, K=12 (kk=144), S=4, 10x10=100 windows, BS=8.
// Output: [8,100,144,144] fp32 = 16,588,800 elems.
// One thread per output float4: 4,147,200 float4 = 16200 blocks x 256 threads.
//
// Round-1 post-mortem: benched dur_us includes ~212us of harness re-poison
// fills (kernel never appears in rocprof top-5 => < ~104us; delta analysis
// puts it at ~19us, near the write-bound floor with the input L3-resident).
// Direct gather + coalesced f4 writes is the right structure; LDS staging
// (Round 1) only added real traffic (+27us).
// Round-2 fix: __builtin_nontemporal_store needs a native clang vector type,
// not HIP_vector_type<float,4> — use ext_vector_type(4) for the store.

namespace {
constexpr int NTOK = 2304;   // N = 48*48
constexpr int NW   = 100;    // windows
constexpr int KK   = 144;    // k*k
constexpr int QPR  = 36;     // float4 per output row (144/4)
constexpr int TOTAL_F4 = 8 * NW * KK * QPR;  // 4,147,200

typedef float f4 __attribute__((ext_vector_type(4)));  // native vec, NT-store ok
}

__global__ __launch_bounds__(256) void submanifold_gather(
    const float* __restrict__ x, f4* __restrict__ out) {
    int t = blockIdx.x * 256 + threadIdx.x;   // exact grid, no bounds check

    int q   = t % QPR;          // which float4 within a 144-long out row
    int rid = t / QPR;          // (b, w, i)
    int i   = rid % KK;
    int bw  = rid / KK;
    int w   = bw % NW;
    int b   = bw / NW;

    int wr = w / 10;
    int wc = w - wr * 10;
    int base = 192 * wr + 4 * wc;          // window's flat token base

    int ai = i / 12;
    int bi = i - ai * 12;
    int r  = base + 48 * ai + bi;          // source row (flat token idx)

    int aj  = q / 3;
    int bj4 = (q - aj * 3) * 4;
    int c   = base + 48 * aj + bj4;        // source col start (mult of 4)

    const f4* src = reinterpret_cast<const f4*>(
        x + (size_t)b * NTOK * NTOK + (size_t)r * NTOK + c);
    f4 v = *src;
    __builtin_nontemporal_store(v, &out[t]);
}

extern "C" void kernel_launch(void* const* d_in, const int* in_sizes, int n_in,
                              void* d_out, int out_size, void* d_ws, size_t ws_size,
                              hipStream_t stream) {
    const float* x = (const float*)d_in[0];
    f4* out = (f4*)d_out;
    const int blocks = TOTAL_F4 / 256;  // 16200, exact
    submanifold_gather<<<blocks, 256, 0, stream>>>(x, out);
}